// Round 10
// baseline (195.787 us; speedup 1.0000x reference)
//
#include <hip/hip_runtime.h>

// AliasFreeSampling via MFMA: separable 65-tap Kaiser-sinc + 2x2 avg pool,
// folded to 66-tap stride-2 filters. Both phases are banded-Toeplitz GEMMs:
//   Phase A: g(row, ow) = sum_k x(row, k) * W(k, ow),  W[k][n] = c[k-2n]
//   Phase B: out(oh, w) = sum_k C(oh, k) * gT(w, k),   C[m][k] = c[k-2m]
// Data: bf16; coefficients: bf16 hi+lo split (6 MFMAs per 16x16x96 tile).
// R9: monolithic tile (64 oh x 32 ow), full 192-row raw window staged in ONE
// coalesced burst -> TWO __syncthreads per block total (vs 7). The barrier
// vmcnt drain happens once, right after the loads were consumed anyway.
// Datapath (frag tables, MFMA layout, RNE pack) identical to passing R6/R7.

#define W_IN 512
#define H_IN 512
#define W_OUT 256
#define H_OUT 256
#define OW_T 32
#define OH_T 64
#define NROW 192          // raw rows = 2*OH_T + 64
#define RSTR 136          // raw row stride (ushorts); 128 data + pad
#define GSTR 200          // gt row stride (ushorts); 192 data + pad

typedef __attribute__((ext_vector_type(8))) short short8;
typedef __attribute__((ext_vector_type(4))) float f32x4;

// ---------- compile-time filter construction ----------
constexpr double csqrt_(double x) {
  double g = x > 1.0 ? x : 1.0;
  for (int i = 0; i < 64; ++i) g = 0.5 * (g + x / g);
  return g;
}
constexpr double i0_(double x) {
  double q = x * x * 0.25, t = 1.0, s = 1.0;
  for (int m = 1; m < 40; ++m) { t *= q / ((double)m * (double)m); s += t; }
  return s;
}
struct CArr { float c[66]; };
constexpr CArr make_c() {
  CArr R{};
  double k[65] = {};
  const double r = csqrt_(0.5);
  const double pi = 3.14159265358979323846;
  const double i0b = i0_(8.0);
  double stab[8] = {0.0, r, 1.0, r, 0.0, -r, -1.0, -r};  // sin(pi*n/4)
  double sum = 0.0;
  for (int i = 0; i < 65; ++i) {
    int n = i - 32;
    double sv;
    if (n == 0) sv = 0.25;
    else {
      int m = ((n % 8) + 8) % 8;
      sv = stab[m] / (pi * 0.25 * (double)n);
    }
    double t = (2.0 * i - 65.0) / 65.0;  // kaiser(66)[i]
    double a = 1.0 - t * t;
    double w = i0_(8.0 * csqrt_(a < 0.0 ? 0.0 : a)) / i0b;
    k[i] = sv * w;
    sum += k[i];
  }
  for (int i = 0; i < 65; ++i) k[i] /= sum;
  for (int s = 0; s < 66; ++s) {
    double a = s < 65 ? k[s] : 0.0;
    double b = s > 0 ? k[s - 1] : 0.0;
    R.c[s] = (float)(0.5 * (a + b));
  }
  return R;
}
constexpr CArr CC = make_c();

__device__ __forceinline__ unsigned bf16_rne(float f) {
  unsigned u = __float_as_uint(f);
  return (u + 0x7FFFu + ((u >> 16) & 1u)) >> 16;
}
__device__ __forceinline__ int refl(int i, int n) {
  if (i < 0) i = -i;
  if (i >= n) i = 2 * n - 2 - i;
  return i;
}

// Coef fragment table: hi[3][64][8], lo[3][64][8] bf16 (as ushort).
// Per-lane value c[ktot - 2*(lane&15)] serves BOTH operand roles.
__global__ void afs_init_frag(unsigned short* cw) {
  int t = threadIdx.x;
  if (t >= 192) return;
  int kb = t >> 6, l = t & 63;
  for (int j = 0; j < 8; ++j) {
    int ktot = 32 * kb + 8 * (l >> 4) + j;
    int idx = ktot - 2 * (l & 15);
    float v = (idx >= 0 && idx < 66) ? CC.c[idx] : 0.0f;
    unsigned hi = bf16_rne(v);
    float res = v - __uint_as_float(hi << 16);
    unsigned lo = bf16_rne(res);
    cw[(kb * 64 + l) * 8 + j] = (unsigned short)hi;
    cw[1536 + (kb * 64 + l) * 8 + j] = (unsigned short)lo;
  }
}

__global__ __launch_bounds__(512, 4) void afs_mono(
    const float* __restrict__ x, const unsigned short* __restrict__ cw,
    float* __restrict__ out) {
  __shared__ __attribute__((aligned(16))) unsigned short raw[NROW * RSTR]; // 52.2 KB
  __shared__ __attribute__((aligned(16))) unsigned short gt[OW_T * GSTR];  // 12.8 KB

  const int plane = blockIdx.z;
  const int OH0 = blockIdx.y * OH_T;
  const int OW0 = blockIdx.x * OW_T;
  const int W0 = 2 * OW0 - 32;               // 128-float raw window start
  const int rb = 2 * OH0 - 32;
  const bool edge = (blockIdx.x == 0) || (blockIdx.x == gridDim.x - 1);
  const float* xp = x + (size_t)plane * (W_IN * H_IN);
  float* op = out + (size_t)plane * (W_OUT * H_OUT);
  const int tid = threadIdx.x;
  const int lane = tid & 63;
  const int wave = tid >> 6;          // [0,8)
  const int la = lane & 15;
  const int lg = lane >> 4;           // [0,4)

  // coefficient fragments (shared A/B-operand layout)
  short8 ch[3], cl[3];
#pragma unroll
  for (int kb = 0; kb < 3; ++kb) {
    ch[kb] = ((const short8*)cw)[kb * 64 + lane];
    cl[kb] = ((const short8*)cw)[192 + kb * 64 + lane];
  }

  // ---- stage: 192 rows x 32 float4-slots = 6144 tasks, 12/thread.
  // One burst of 12 independent loads -> single latency exposure.
  float4 pf[12];
#pragma unroll
  for (int i = 0; i < 12; ++i) {
    int f = i * 512 + tid;
    int r = f >> 5;                   // raw row [0,192)
    int s = f & 31;                   // float4 slot [0,32)
    int h = refl(rb + r, H_IN);
    const float* xrow = xp + (size_t)h * W_IN;
    int c0 = W0 + 4 * s;
    if (!edge || (c0 >= 0 && c0 + 4 <= W_IN)) {
      pf[i] = *(const float4*)(xrow + c0);
    } else {
      pf[i].x = xrow[refl(c0 + 0, W_IN)];
      pf[i].y = xrow[refl(c0 + 1, W_IN)];
      pf[i].z = xrow[refl(c0 + 2, W_IN)];
      pf[i].w = xrow[refl(c0 + 3, W_IN)];
    }
  }
#pragma unroll
  for (int i = 0; i < 12; ++i) {
    int f = i * 512 + tid;
    int r = f >> 5;
    int s = f & 31;
    unsigned h0 = bf16_rne(pf[i].x) | (bf16_rne(pf[i].y) << 16);
    unsigned h1 = bf16_rne(pf[i].z) | (bf16_rne(pf[i].w) << 16);
    uint2 pk = {h0, h1};
    *(uint2*)&raw[r * RSTR + 4 * s] = pk;
  }
  __syncthreads();

  // ---- Phase A: 24 subtiles (12 row-blocks x 2 ow-blocks), 3 per wave ----
#pragma unroll
  for (int i = 0; i < 3; ++i) {
    int id = wave + 8 * i;            // [0,24)
    int rb_ = id >> 1;                // raw row-block [0,12)
    int wb = id & 1;                  // ow-block [0,2)
    const unsigned short* ar = &raw[(16 * rb_ + la) * RSTR + 32 * wb + 8 * lg];
    short8 a0 = *(const short8*)(ar + 0);
    short8 a1 = *(const short8*)(ar + 32);
    short8 a2 = *(const short8*)(ar + 64);
    f32x4 acc = {0.f, 0.f, 0.f, 0.f};
    acc = __builtin_amdgcn_mfma_f32_16x16x32_bf16(a0, ch[0], acc, 0, 0, 0);
    acc = __builtin_amdgcn_mfma_f32_16x16x32_bf16(a1, ch[1], acc, 0, 0, 0);
    acc = __builtin_amdgcn_mfma_f32_16x16x32_bf16(a2, ch[2], acc, 0, 0, 0);
    acc = __builtin_amdgcn_mfma_f32_16x16x32_bf16(a0, cl[0], acc, 0, 0, 0);
    acc = __builtin_amdgcn_mfma_f32_16x16x32_bf16(a1, cl[1], acc, 0, 0, 0);
    acc = __builtin_amdgcn_mfma_f32_16x16x32_bf16(a2, cl[2], acc, 0, 0, 0);
    // D: row m = 4*lg + r (raw row), col n = la (ow). Write transposed:
    // gt[ow = 16*wb+la][grow = 16*rb_ + 4*lg + r], r contiguous.
    unsigned g0 = bf16_rne(acc[0]) | (bf16_rne(acc[1]) << 16);
    unsigned g1 = bf16_rne(acc[2]) | (bf16_rne(acc[3]) << 16);
    uint2 pk = {g0, g1};
    *(uint2*)&gt[(16 * wb + la) * GSTR + 16 * rb_ + 4 * lg] = pk;
  }
  __syncthreads();

  // ---- Phase B: 8 subtiles (4 oh-blocks x 2 w-blocks), 1 per wave ----
  {
    int os = wave >> 1;               // oh block [0,4)
    int wsub = wave & 1;              // w block [0,2)
    const unsigned short* br = &gt[(16 * wsub + la) * GSTR + 32 * os + 8 * lg];
    short8 b0 = *(const short8*)(br + 0);
    short8 b1 = *(const short8*)(br + 32);
    short8 b2 = *(const short8*)(br + 64);
    f32x4 acc = {0.f, 0.f, 0.f, 0.f};
    acc = __builtin_amdgcn_mfma_f32_16x16x32_bf16(ch[0], b0, acc, 0, 0, 0);
    acc = __builtin_amdgcn_mfma_f32_16x16x32_bf16(ch[1], b1, acc, 0, 0, 0);
    acc = __builtin_amdgcn_mfma_f32_16x16x32_bf16(ch[2], b2, acc, 0, 0, 0);
    acc = __builtin_amdgcn_mfma_f32_16x16x32_bf16(cl[0], b0, acc, 0, 0, 0);
    acc = __builtin_amdgcn_mfma_f32_16x16x32_bf16(cl[1], b1, acc, 0, 0, 0);
    acc = __builtin_amdgcn_mfma_f32_16x16x32_bf16(cl[2], b2, acc, 0, 0, 0);
    // D: row = oh offset 4*lg + r, col = w offset la
    int ow = OW0 + 16 * wsub + la;
#pragma unroll
    for (int r = 0; r < 4; ++r) {
      int oh = OH0 + 16 * os + 4 * lg + r;
      op[(size_t)oh * W_OUT + ow] = acc[r];
    }
  }
}

extern "C" void kernel_launch(void* const* d_in, const int* in_sizes, int n_in,
                              void* d_out, int out_size, void* d_ws, size_t ws_size,
                              hipStream_t stream) {
  const float* x = (const float*)d_in[0];       // (8,32,512,512) fp32
  float* out = (float*)d_out;                   // (8,32,256,256) fp32
  unsigned short* cw = (unsigned short*)d_ws;   // 3072 ushorts coef frags

  afs_init_frag<<<1, 192, 0, stream>>>(cw);

  dim3 grid(W_OUT / OW_T, H_OUT / OH_T, 256);   // 8 x 4 x 256
  afs_mono<<<grid, 512, 0, stream>>>(x, cw, out);
}

// Round 11
// 190.145 us; speedup vs baseline: 1.0297x; 1.0297x over previous
//
#include <hip/hip_runtime.h>

// AliasFreeSampling via MFMA: separable 65-tap Kaiser-sinc + 2x2 avg pool,
// folded to 66-tap stride-2 filters. Both phases are banded-Toeplitz GEMMs:
//   Phase A: g(row, ow) = sum_k x(row, k) * W(k, ow),  W[k][n] = c[k-2n]
//   Phase B: out(oh, w) = sum_k C(oh, k) * gT(w, k),   C[m][k] = c[k-2m]
// Data: bf16; coefficients: bf16 hi+lo split (6 MFMAs per 16x16x96 tile).
// R10: R7 datapath unchanged; concurrency restructured:
//  - 256-thread blocks, 64x32 tile -> 30.2 KB LDS -> 5 blocks/CU
//    (5 independent barrier domains cover each other's vmcnt drains)
//  - bijective XCD swizzle: 32 whole planes per XCD -> halo reuse is
//    same-XCD-L2-hot (halo re-read latency 900 -> ~200 cy)
//  - prefetch issued AFTER Phase A; its wait is per-wave (WRITER), not
//    a block-wide barrier drain.

#define W_IN 512
#define H_IN 512
#define W_OUT 256
#define H_OUT 256
#define OW_T 32
#define OH_T 64
#define RSTR 136          // raw row stride (ushorts): 128 data + 8 pad
#define GSTR 200          // gt row stride (ushorts): 192 data + 8 pad
#define NCH 6             // 6 chunks x 32 raw rows

typedef __attribute__((ext_vector_type(8))) short short8;
typedef __attribute__((ext_vector_type(4))) float f32x4;

// ---------- compile-time filter construction ----------
constexpr double csqrt_(double x) {
  double g = x > 1.0 ? x : 1.0;
  for (int i = 0; i < 64; ++i) g = 0.5 * (g + x / g);
  return g;
}
constexpr double i0_(double x) {
  double q = x * x * 0.25, t = 1.0, s = 1.0;
  for (int m = 1; m < 40; ++m) { t *= q / ((double)m * (double)m); s += t; }
  return s;
}
struct CArr { float c[66]; };
constexpr CArr make_c() {
  CArr R{};
  double k[65] = {};
  const double r = csqrt_(0.5);
  const double pi = 3.14159265358979323846;
  const double i0b = i0_(8.0);
  double stab[8] = {0.0, r, 1.0, r, 0.0, -r, -1.0, -r};  // sin(pi*n/4)
  double sum = 0.0;
  for (int i = 0; i < 65; ++i) {
    int n = i - 32;
    double sv;
    if (n == 0) sv = 0.25;
    else {
      int m = ((n % 8) + 8) % 8;
      sv = stab[m] / (pi * 0.25 * (double)n);
    }
    double t = (2.0 * i - 65.0) / 65.0;  // kaiser(66)[i]
    double a = 1.0 - t * t;
    double w = i0_(8.0 * csqrt_(a < 0.0 ? 0.0 : a)) / i0b;
    k[i] = sv * w;
    sum += k[i];
  }
  for (int i = 0; i < 65; ++i) k[i] /= sum;
  for (int s = 0; s < 66; ++s) {
    double a = s < 65 ? k[s] : 0.0;
    double b = s > 0 ? k[s - 1] : 0.0;
    R.c[s] = (float)(0.5 * (a + b));
  }
  return R;
}
constexpr CArr CC = make_c();

__device__ __forceinline__ unsigned bf16_rne(float f) {
  unsigned u = __float_as_uint(f);
  return (u + 0x7FFFu + ((u >> 16) & 1u)) >> 16;
}
__device__ __forceinline__ int refl(int i, int n) {
  if (i < 0) i = -i;
  if (i >= n) i = 2 * n - 2 - i;
  return i;
}

// Coef fragment table: hi[3][64][8], lo[3][64][8] bf16 (as ushort).
// Per-lane value c[ktot - 2*(lane&15)] serves BOTH operand roles.
__global__ void afs_init_frag(unsigned short* cw) {
  int t = threadIdx.x;
  if (t >= 192) return;
  int kb = t >> 6, l = t & 63;
  for (int j = 0; j < 8; ++j) {
    int ktot = 32 * kb + 8 * (l >> 4) + j;
    int idx = ktot - 2 * (l & 15);
    float v = (idx >= 0 && idx < 66) ? CC.c[idx] : 0.0f;
    unsigned hi = bf16_rne(v);
    float res = v - __uint_as_float(hi << 16);
    unsigned lo = bf16_rne(res);
    cw[(kb * 64 + l) * 8 + j] = (unsigned short)hi;
    cw[1536 + (kb * 64 + l) * 8 + j] = (unsigned short)lo;
  }
}

#define LOADC(base_k)                                                      \
  {                                                                        \
    _Pragma("unroll") for (int it = 0; it < 4; ++it) {                     \
      int h = refl(rb + 32 * (base_k) + sr[it], H_IN);                     \
      const float* xrow = xp + (size_t)h * W_IN;                           \
      if (sin_[it]) {                                                      \
        pf[it] = *(const float4*)(xrow + sc[it]);                          \
      } else {                                                             \
        pf[it].x = xrow[refl(sc[it] + 0, W_IN)];                           \
        pf[it].y = xrow[refl(sc[it] + 1, W_IN)];                           \
        pf[it].z = xrow[refl(sc[it] + 2, W_IN)];                           \
        pf[it].w = xrow[refl(sc[it] + 3, W_IN)];                           \
      }                                                                    \
    }                                                                      \
  }

__global__ __launch_bounds__(256, 5) void afs_mfma(
    const float* __restrict__ x, const unsigned short* __restrict__ cw,
    float* __restrict__ out) {
  __shared__ unsigned short raw[2][32 * RSTR];  // 2 x 8.7 KB bf16 chunks
  __shared__ unsigned short gt[OW_T * GSTR];    // 12.8 KB bf16 g transposed

  // bijective XCD swizzle: dispatch order n (x-fastest) round-robins XCDs;
  // v = (n&7)*1024 + n>>3 puts 32 consecutive planes on each XCD.
  const int n = blockIdx.x + 8 * blockIdx.y + 32 * blockIdx.z;
  const int v = (n & 7) * 1024 + (n >> 3);
  const int plane = v >> 5;
  const int by = (v & 31) >> 3;
  const int bx = v & 7;

  const int OH0 = by * OH_T;
  const int OW0 = bx * OW_T;
  const int W0 = 2 * OW0 - 32;        // 128-float raw window start
  const int rb = 2 * OH0 - 32;
  const float* xp = x + (size_t)plane * (W_IN * H_IN);
  float* op = out + (size_t)plane * (W_OUT * H_OUT);
  const int tid = threadIdx.x;
  const int lane = tid & 63;
  const int wave = tid >> 6;          // [0,4)
  const int la = lane & 15;
  const int lg = lane >> 4;           // [0,4)

  // coefficient fragments (shared A/B-operand layout)
  short8 ch[3], cl[3];
#pragma unroll
  for (int kb = 0; kb < 3; ++kb) {
    ch[kb] = ((const short8*)cw)[kb * 64 + lane];
    cl[kb] = ((const short8*)cw)[192 + kb * 64 + lane];
  }

  // staging task coords: 32 rows x 32 float4-slots = 1024 tasks, 4/thread
  int sr[4], sc[4];
  bool sin_[4];
#pragma unroll
  for (int it = 0; it < 4; ++it) {
    int f = it * 256 + tid;           // [0,1024)
    sr[it] = f >> 5;                  // raw row [0,32)
    int s = f & 31;                   // float4 slot [0,32)
    sc[it] = W0 + 4 * s;
    sin_[it] = (sc[it] >= 0) && (sc[it] + 4 <= W_IN);
  }

  // wave -> Phase-A subtile: 2 row-blocks x 2 ow-blocks per chunk
  const int rs = wave >> 1;           // [0,2)
  const int ws = wave & 1;            // [0,2)

  float4 pf[4];
  LOADC(0);

  for (int k = 0; k < NCH; ++k) {
    unsigned short* rk = &raw[k & 1][0];

    // ---- write raw(k) as bf16 (waits on this wave's vmcnt only) ----
#pragma unroll
    for (int it = 0; it < 4; ++it) {
      unsigned h0 = bf16_rne(pf[it].x) | (bf16_rne(pf[it].y) << 16);
      unsigned h1 = bf16_rne(pf[it].z) | (bf16_rne(pf[it].w) << 16);
      uint2 pk = {h0, h1};
      *(uint2*)&rk[sr[it] * RSTR + (sc[it] - W0)] = pk;
    }

    __syncthreads();   // raw(k) visible; A(k-2) readers done with buf k&1

    // ---- Phase A: 16 raw rows x 16 ow cols via 6 MFMAs ----
    {
      const unsigned short* ar = &rk[(16 * rs + la) * RSTR + 32 * ws + 8 * lg];
      short8 a0 = *(const short8*)(ar + 0);
      short8 a1 = *(const short8*)(ar + 32);
      short8 a2 = *(const short8*)(ar + 64);
      f32x4 acc = {0.f, 0.f, 0.f, 0.f};
      acc = __builtin_amdgcn_mfma_f32_16x16x32_bf16(a0, ch[0], acc, 0, 0, 0);
      acc = __builtin_amdgcn_mfma_f32_16x16x32_bf16(a1, ch[1], acc, 0, 0, 0);
      acc = __builtin_amdgcn_mfma_f32_16x16x32_bf16(a2, ch[2], acc, 0, 0, 0);
      acc = __builtin_amdgcn_mfma_f32_16x16x32_bf16(a0, cl[0], acc, 0, 0, 0);
      acc = __builtin_amdgcn_mfma_f32_16x16x32_bf16(a1, cl[1], acc, 0, 0, 0);
      acc = __builtin_amdgcn_mfma_f32_16x16x32_bf16(a2, cl[2], acc, 0, 0, 0);
      // D: row m=4*lg+r (raw row), col n=la (ow). Write transposed:
      // gt[ow = 16*ws+la][grow = 32*k + 16*rs + 4*lg + r], r contiguous.
      unsigned g0 = bf16_rne(acc[0]) | (bf16_rne(acc[1]) << 16);
      unsigned g1 = bf16_rne(acc[2]) | (bf16_rne(acc[3]) << 16);
      uint2 pk = {g0, g1};
      *(uint2*)&gt[(16 * ws + la) * GSTR + 32 * k + 16 * rs + 4 * lg] = pk;
    }

    // ---- issue chunk k+1 loads (latency covered by other waves/blocks) ----
    if (k + 1 < NCH) LOADC(k + 1);
  }
  __syncthreads();

  // ---- Phase B: 8 subtiles (4 oh-blocks x 2 w-blocks), 2 per wave ----
#pragma unroll
  for (int i = 0; i < 2; ++i) {
    int id = wave + 4 * i;            // [0,8)
    int os = id >> 1;                 // oh block [0,4)
    int wsub = id & 1;                // w block [0,2)
    const unsigned short* br = &gt[(16 * wsub + la) * GSTR + 32 * os + 8 * lg];
    short8 b0 = *(const short8*)(br + 0);
    short8 b1 = *(const short8*)(br + 32);
    short8 b2 = *(const short8*)(br + 64);
    f32x4 acc = {0.f, 0.f, 0.f, 0.f};
    acc = __builtin_amdgcn_mfma_f32_16x16x32_bf16(ch[0], b0, acc, 0, 0, 0);
    acc = __builtin_amdgcn_mfma_f32_16x16x32_bf16(ch[1], b1, acc, 0, 0, 0);
    acc = __builtin_amdgcn_mfma_f32_16x16x32_bf16(ch[2], b2, acc, 0, 0, 0);
    acc = __builtin_amdgcn_mfma_f32_16x16x32_bf16(cl[0], b0, acc, 0, 0, 0);
    acc = __builtin_amdgcn_mfma_f32_16x16x32_bf16(cl[1], b1, acc, 0, 0, 0);
    acc = __builtin_amdgcn_mfma_f32_16x16x32_bf16(cl[2], b2, acc, 0, 0, 0);
    // D: row = oh offset 4*lg + r, col = w offset la
    int ow = OW0 + 16 * wsub + la;
#pragma unroll
    for (int r = 0; r < 4; ++r) {
      int oh = OH0 + 16 * os + 4 * lg + r;
      op[(size_t)oh * W_OUT + ow] = acc[r];
    }
  }
}

extern "C" void kernel_launch(void* const* d_in, const int* in_sizes, int n_in,
                              void* d_out, int out_size, void* d_ws, size_t ws_size,
                              hipStream_t stream) {
  const float* x = (const float*)d_in[0];       // (8,32,512,512) fp32
  float* out = (float*)d_out;                   // (8,32,256,256) fp32
  unsigned short* cw = (unsigned short*)d_ws;   // 3072 ushorts coef frags

  afs_init_frag<<<1, 192, 0, stream>>>(cw);

  dim3 grid(W_OUT / OW_T, H_OUT / OH_T, 256);   // 8 x 4 x 256
  afs_mfma<<<grid, 256, 0, stream>>>(x, cw, out);
}